// Round 1
// baseline (934.746 us; speedup 1.0000x reference)
//
#include <hip/hip_runtime.h>

typedef unsigned short u16;
typedef unsigned int u32;
typedef __attribute__((ext_vector_type(8))) short s8v;
typedef __attribute__((ext_vector_type(8))) __bf16 b8v;
typedef __attribute__((ext_vector_type(4))) float f4v;

#define B_ 8
#define N_ 8192
#define D_ 512
#define H_ 8
#define M_ 64

__device__ __forceinline__ float bf2f(u16 u) { return __uint_as_float(((u32)u) << 16); }
__device__ __forceinline__ u16 f2bf(float f) {
  u32 x = __float_as_uint(f);
  return (u16)((x + 0x7fffu + ((x >> 16) & 1u)) >> 16);  // RNE, inputs are finite
}
__device__ __forceinline__ void unpack2(u32 u, float& a, float& b) {
  a = __uint_as_float(u << 16);
  b = __uint_as_float(u & 0xffff0000u);
}

// async global->LDS, 16B per lane (dest must be wave-uniform base + lane*16)
__device__ __forceinline__ void gload_lds16(const void* g, void* l) {
  __builtin_amdgcn_global_load_lds((const __attribute__((address_space(1))) void*)g,
                                   (__attribute__((address_space(3))) void*)l, 16, 0, 0);
}

// MFMA dispatcher: compiles whether the builtin wants short8 or __bf16x8.
template <typename V>
__device__ __forceinline__ auto mfma_sel(V a, V b, f4v c, int)
    -> decltype(__builtin_amdgcn_mfma_f32_16x16x32_bf16(a, b, c, 0, 0, 0)) {
  return __builtin_amdgcn_mfma_f32_16x16x32_bf16(a, b, c, 0, 0, 0);
}
template <typename V>
__device__ __forceinline__ f4v mfma_sel(V a, V b, f4v c, long) {
  return __builtin_amdgcn_mfma_f32_16x16x32_bf16(__builtin_bit_cast(b8v, a),
                                                 __builtin_bit_cast(b8v, b), c, 0, 0, 0);
}
__device__ __forceinline__ f4v MFMA(s8v a, s8v b, f4v c) { return mfma_sel(a, b, c, 0); }

// ---------------------------------------------------------------------------
// Generic NT GEMM: C[M x Ncol] = A[M x K] * Bt[Ncol x K]^T  (bf16 in, f32 acc)
// Batched via blockIdx.z: z -> (zb = z/zh, zr = z%zh), per-operand offsets.
// m97 structure: BK=32, double-buffered LDS, global_load_lds width 16.
// ---------------------------------------------------------------------------
template <int BM, int BN, int WR, int WC, bool OUTBF, bool BIAS>
__launch_bounds__(256)
__global__ void gemm_nt(const u16* __restrict__ A, const u16* __restrict__ Bt,
                        void* __restrict__ Cout, const float* __restrict__ bias,
                        int M, int Ncol, int K, long lda, long ldb, long ldc, int zh,
                        long sAb, long sAh, long sBb, long sBh, long sCb, long sCh) {
  constexpr int NTH = 256;
  constexpr int WM = BM / WR, WN = BN / WC;
  constexpr int MR = WM / 16, NR = WN / 16;
  constexpr int AISS = (BM * 64) / (NTH * 16);
  constexpr int BISS = (BN * 64) / (NTH * 16);
  __shared__ __align__(16) u16 As[2][BM][32];
  __shared__ __align__(16) u16 Bs[2][BN][32];

  const int tid = threadIdx.x;
  const int z = blockIdx.z;
  const int zb = z / zh, zr = z % zh;
  const u16* Ab = A + zb * sAb + zr * sAh;
  const u16* Bb = Bt + zb * sBb + zr * sBh;
  const long tm = (long)blockIdx.y * BM;
  const long tn = (long)blockIdx.x * BN;
  const int lane = tid & 63, wid = tid >> 6;
  const int wr = wid / WC, wc = wid % WC;

  f4v acc[MR][NR] = {};

  auto stage = [&](int buf, int k0) {
#pragma unroll
    for (int i = 0; i < AISS; ++i) {
      const int t = i * NTH + tid;
      gload_lds16((const char*)Ab + ((tm + (t >> 2)) * lda + k0) * 2 + (t & 3) * 16,
                  (char*)(&As[buf][0][0]) + t * 16);
    }
#pragma unroll
    for (int i = 0; i < BISS; ++i) {
      const int t = i * NTH + tid;
      gload_lds16((const char*)Bb + ((tn + (t >> 2)) * ldb + k0) * 2 + (t & 3) * 16,
                  (char*)(&Bs[buf][0][0]) + t * 16);
    }
  };

  stage(0, 0);
  const int NK = K >> 5;
  for (int kt = 0; kt < NK; ++kt) {
    __syncthreads();  // drains vmcnt -> staged buffer ready; protects buffer reuse
    if (kt + 1 < NK) stage((kt + 1) & 1, (kt + 1) << 5);
    const int cb = kt & 1;
    s8v av[MR];
    s8v bv[NR];
#pragma unroll
    for (int i = 0; i < MR; ++i)
      av[i] = *(const s8v*)&As[cb][wr * WM + i * 16 + (lane & 15)][(lane >> 4) * 8];
#pragma unroll
    for (int j = 0; j < NR; ++j)
      bv[j] = *(const s8v*)&Bs[cb][wc * WN + j * 16 + (lane & 15)][(lane >> 4) * 8];
#pragma unroll
    for (int i = 0; i < MR; ++i) {
#pragma unroll
      for (int j = 0; j < NR; ++j) acc[i][j] = MFMA(av[i], bv[j], acc[i][j]);
    }
  }

  // C/D layout (verified m89/m91): col = lane&15, row = (lane>>4)*4 + reg
  const long zco = zb * sCb + zr * sCh;
  const long row0 = tm + wr * WM + ((lane >> 4) << 2);
  const long col0 = tn + wc * WN + (lane & 15);
#pragma unroll
  for (int i = 0; i < MR; ++i) {
#pragma unroll
    for (int j = 0; j < NR; ++j) {
#pragma unroll
      for (int r = 0; r < 4; ++r) {
        const long row = row0 + i * 16 + r;
        const long col = col0 + j * 16;
        float v = acc[i][j][r];
        if constexpr (BIAS) v += bias[col];
        if constexpr (OUTBF)
          ((u16*)Cout)[zco + row * ldc + col] = f2bf(v);
        else
          ((float*)Cout)[zco + row * ldc + col] = v;
      }
    }
  }
}

// ---------------------------------------------------------------------------
__launch_bounds__(256)
__global__ void cast_f32_bf16_k(const float* __restrict__ src, u16* __restrict__ dst, long n) {
  const long i = ((long)blockIdx.x * 256 + threadIdx.x) * 8;
  if (i >= n) return;
  const float4* s = (const float4*)(src + i);
  const float4 a = s[0], b = s[1];
  uint4 o;
  o.x = (u32)f2bf(a.x) | ((u32)f2bf(a.y) << 16);
  o.y = (u32)f2bf(a.z) | ((u32)f2bf(a.w) << 16);
  o.z = (u32)f2bf(b.x) | ((u32)f2bf(b.y) << 16);
  o.w = (u32)f2bf(b.z) | ((u32)f2bf(b.w) << 16);
  *(uint4*)(dst + i) = o;
}

__launch_bounds__(256)
__global__ void transpose_cast_k(const float* __restrict__ src, u16* __restrict__ dst, int R, int C) {
  const long idx = (long)blockIdx.x * 256 + threadIdx.x;
  if (idx >= (long)R * C) return;
  const int r = (int)(idx / C), c = (int)(idx - (long)r * C);
  dst[(long)c * R + r] = f2bf(src[idx]);
}

// softmax over m (64 contiguous values per (b,n,h)) — in place on bf16 rows
__launch_bounds__(256)
__global__ void softmax_m_k(u16* __restrict__ sw) {
  const long g = (long)blockIdx.x * 32 + (threadIdx.x >> 3);
  const int h = threadIdx.x & 7;
  u16* p = sw + g * 512 + h * 64;
  float v[64];
  const uint4* q = (const uint4*)p;
#pragma unroll
  for (int i = 0; i < 8; ++i) {
    const uint4 u = q[i];
    unpack2(u.x, v[i * 8 + 0], v[i * 8 + 1]);
    unpack2(u.y, v[i * 8 + 2], v[i * 8 + 3]);
    unpack2(u.z, v[i * 8 + 4], v[i * 8 + 5]);
    unpack2(u.w, v[i * 8 + 6], v[i * 8 + 7]);
  }
  float mx = v[0];
#pragma unroll
  for (int i = 1; i < 64; ++i) mx = fmaxf(mx, v[i]);
  float s = 0.f;
#pragma unroll
  for (int i = 0; i < 64; ++i) {
    v[i] = __expf(v[i] - mx);
    s += v[i];
  }
  const float inv = 1.f / s;
  uint4* o = (uint4*)p;
#pragma unroll
  for (int i = 0; i < 8; ++i) {
    uint4 u;
    u.x = (u32)f2bf(v[i * 8 + 0] * inv) | ((u32)f2bf(v[i * 8 + 1] * inv) << 16);
    u.y = (u32)f2bf(v[i * 8 + 2] * inv) | ((u32)f2bf(v[i * 8 + 3] * inv) << 16);
    u.z = (u32)f2bf(v[i * 8 + 4] * inv) | ((u32)f2bf(v[i * 8 + 5] * inv) << 16);
    u.w = (u32)f2bf(v[i * 8 + 6] * inv) | ((u32)f2bf(v[i * 8 + 7] * inv) << 16);
    o[i] = u;
  }
}

// slice_tok accumulation: acc[b,h,m,d] += sum_n w[b,h,m,n]*xv[b,h,n,d]; S += sum_n w
__launch_bounds__(256)
__global__ void slice_acc_k(const u16* __restrict__ swT, const u16* __restrict__ kv,
                            float* __restrict__ acc, float* __restrict__ Ssum) {
  const int z = blockIdx.x;  // 512 = (b,h) x 8 chunks
  const int chunk = z & 7, bh = z >> 3;
  const int b = bh >> 3, h = bh & 7;
  const int tid = threadIdx.x;
  const int m = tid & 63, dg = tid >> 6;
  const u16* wp = swT + ((long)b * N_ + (long)chunk * 1024) * 512 + h * 64 + m;
  const u16* xp = kv + ((long)b * N_ + (long)chunk * 1024) * 1024 + 512 + h * 64 + dg * 16;
  float a[16];
#pragma unroll
  for (int j = 0; j < 16; ++j) a[j] = 0.f;
  float s = 0.f;
  for (int n = 0; n < 1024; ++n) {
    const float w = bf2f(*wp);
    wp += 512;
    const uint4* x4 = (const uint4*)xp;
    const uint4 u0 = x4[0], u1 = x4[1];
    xp += 1024;
    s += w;
    float e0, e1;
    unpack2(u0.x, e0, e1); a[0] = fmaf(w, e0, a[0]); a[1] = fmaf(w, e1, a[1]);
    unpack2(u0.y, e0, e1); a[2] = fmaf(w, e0, a[2]); a[3] = fmaf(w, e1, a[3]);
    unpack2(u0.z, e0, e1); a[4] = fmaf(w, e0, a[4]); a[5] = fmaf(w, e1, a[5]);
    unpack2(u0.w, e0, e1); a[6] = fmaf(w, e0, a[6]); a[7] = fmaf(w, e1, a[7]);
    unpack2(u1.x, e0, e1); a[8] = fmaf(w, e0, a[8]); a[9] = fmaf(w, e1, a[9]);
    unpack2(u1.y, e0, e1); a[10] = fmaf(w, e0, a[10]); a[11] = fmaf(w, e1, a[11]);
    unpack2(u1.z, e0, e1); a[12] = fmaf(w, e0, a[12]); a[13] = fmaf(w, e1, a[13]);
    unpack2(u1.w, e0, e1); a[14] = fmaf(w, e0, a[14]); a[15] = fmaf(w, e1, a[15]);
  }
  float* ap = acc + ((long)bh * 64 + m) * 64 + dg * 16;
#pragma unroll
  for (int j = 0; j < 16; ++j) atomicAdd(ap + j, a[j]);
  if (dg == 0) atomicAdd(Ssum + bh * 64 + m, s);
}

// normalize by S, layernorm over d, emit slice_tok as [B, M, H*64+d] bf16
__launch_bounds__(256)
__global__ void norm_ln_k(const float* __restrict__ acc, const float* __restrict__ Ssum,
                          const float* __restrict__ g, const float* __restrict__ bb,
                          u16* __restrict__ stok) {
  const int r = blockIdx.x * 4 + (threadIdx.x >> 6);  // 0..4095 = (b,h,m)
  const int d = threadIdx.x & 63;
  const float v = acc[(long)r * 64 + d] / (Ssum[r] + 1e-5f);
  float mu = v;
#pragma unroll
  for (int k = 1; k < 64; k <<= 1) mu += __shfl_xor(mu, k);
  mu *= (1.f / 64.f);
  const float t = v - mu;
  float var = t * t;
#pragma unroll
  for (int k = 1; k < 64; k <<= 1) var += __shfl_xor(var, k);
  var *= (1.f / 64.f);
  const float o = t * rsqrtf(var + 1e-5f) * g[d] + bb[d];
  const int b = r >> 9, h = (r >> 6) & 7, m = r & 63;
  stok[((long)(b * 64 + m)) * 512 + h * 64 + d] = f2bf(o);
}

// tiny per-(b,h) self-attention over M=64 slice tokens; emits out_tok TRANSPOSED [bh][d][m]
__launch_bounds__(256)
__global__ void mini_attn_k(const u16* __restrict__ qkv, u16* __restrict__ otokT) {
  const int bh = blockIdx.x;
  const int b = bh >> 3, h = bh & 7;
  const int tid = threadIdx.x;
  __shared__ u16 qs[64][64], ks[64][64], vs[64][64];
  __shared__ float att[64][64];
  for (int idx = tid; idx < 4096; idx += 256) {
    const int mm = idx >> 6, dd = idx & 63;
    const long base = ((long)(b * 64 + mm)) * 1536 + h * 64 + dd;
    qs[mm][dd] = qkv[base];
    ks[mm][dd] = qkv[base + 512];
    vs[mm][dd] = qkv[base + 1024];
  }
  __syncthreads();
  {
    const int qi = tid >> 2, pt = tid & 3;
    for (int kk = pt * 16; kk < pt * 16 + 16; ++kk) {
      float sum = 0.f;
#pragma unroll
      for (int dd = 0; dd < 64; ++dd) sum += bf2f(qs[qi][dd]) * bf2f(ks[kk][dd]);
      att[qi][kk] = sum * 0.125f;  // HD^-0.5
    }
  }
  __syncthreads();
  if (tid < 64) {
    float mx = att[tid][0];
    for (int k = 1; k < 64; ++k) mx = fmaxf(mx, att[tid][k]);
    float s = 0.f;
    for (int k = 0; k < 64; ++k) {
      const float e = __expf(att[tid][k] - mx);
      att[tid][k] = e;
      s += e;
    }
    const float inv = 1.f / s;
    for (int k = 0; k < 64; ++k) att[tid][k] *= inv;
  }
  __syncthreads();
  {
    const int mi = tid >> 2, pt = tid & 3;
    for (int dd = pt * 16; dd < pt * 16 + 16; ++dd) {
      float sum = 0.f;
#pragma unroll
      for (int k = 0; k < 64; ++k) sum += att[mi][k] * bf2f(vs[k][dd]);
      otokT[((long)bh * 64 + dd) * 64 + mi] = f2bf(sum);
    }
  }
}

// ---------------------------------------------------------------------------
extern "C" void kernel_launch(void* const* d_in, const int* in_sizes, int n_in,
                              void* d_out, int out_size, void* d_ws, size_t ws_size,
                              hipStream_t stream) {
  const float* x = (const float*)d_in[0];
  const float* W_kv = (const float*)d_in[1];
  const float* b_kv = (const float*)d_in[2];
  const float* wtq = (const float*)d_in[3];
  const float* W_mix = (const float*)d_in[4];
  const float* ln_g = (const float*)d_in[5];
  const float* ln_b = (const float*)d_in[6];
  const float* W_qkv = (const float*)d_in[7];
  const float* W_out = (const float*)d_in[8];
  const float* b_out = (const float*)d_in[9];
  float* out = (float*)d_out;
  (void)in_sizes; (void)n_in; (void)out_size; (void)ws_size;

  char* p = (char*)d_ws;
  auto carve = [&](size_t bytes) {
    char* r = p;
    p += (bytes + 255) & ~(size_t)255;
    return r;
  };
  u16* x_bf  = (u16*)carve((size_t)B_ * N_ * D_ * 2);        // 67 MB
  u16* kv_bf = (u16*)carve((size_t)B_ * N_ * 2 * D_ * 2);    // 134 MB
  u16* sw    = (u16*)carve((size_t)B_ * N_ * 512 * 2);       // scoresT -> slice_wT (in-place)
  u16* s0T   = (u16*)carve((size_t)B_ * N_ * 512 * 2);       // scores0T, reused as y_bf
  u16* wkvT  = (u16*)carve((size_t)1024 * 512 * 2);
  u16* wqkvT = (u16*)carve((size_t)1536 * 512 * 2);
  u16* woutT = (u16*)carve((size_t)512 * 512 * 2);
  u16* wmixB = (u16*)carve((size_t)512 * 512 * 2);
  u16* wtqB  = (u16*)carve((size_t)512 * 64 * 2);
  float* sacc = (float*)carve((size_t)4096 * 64 * 4);        // 1 MB (f32 split-K acc)
  float* Ssum = (float*)carve((size_t)4096 * 4);
  u16* stokB = (u16*)carve((size_t)512 * 512 * 2);
  u16* qkvB  = (u16*)carve((size_t)512 * 1536 * 2);
  u16* otokT = (u16*)carve((size_t)4096 * 64 * 2);
  u16* y_bf = s0T;

  // input casts / weight transposes (all GEMMs are NT: A[M][K], Bt[N][K])
  cast_f32_bf16_k<<<(B_ * N_ * D_) / 2048, 256, 0, stream>>>(x, x_bf, (long)B_ * N_ * D_);
  transpose_cast_k<<<(512 * 1024) / 256, 256, 0, stream>>>(W_kv, wkvT, 512, 1024);
  transpose_cast_k<<<(512 * 1536) / 256, 256, 0, stream>>>(W_qkv, wqkvT, 512, 1536);
  transpose_cast_k<<<(512 * 512) / 256, 256, 0, stream>>>(W_out, woutT, 512, 512);
  cast_f32_bf16_k<<<(512 * 512) / 2048, 256, 0, stream>>>(W_mix, wmixB, 512 * 512);
  cast_f32_bf16_k<<<(512 * 64) / 2048, 256, 0, stream>>>(wtq, wtqB, 512 * 64);
  hipMemsetAsync(sacc, 0, (size_t)4096 * 64 * 4 + (size_t)4096 * 4, stream);

  // 1) kv = x @ W_kv + b_kv                      [65536 x 1024]
  gemm_nt<128, 128, 2, 2, true, true><<<dim3(8, 512, 1), 256, 0, stream>>>(
      x_bf, wkvT, kv_bf, b_kv, 65536, 1024, 512, 512, 512, 1024, 1, 0, 0, 0, 0, 0, 0);
  // 2) scores0T[b][n][h*64+m] = xk[b,h,n,:] . wtq[h,m,:]   (per (b,h), K=64)
  gemm_nt<128, 64, 2, 2, true, false><<<dim3(1, 64, 64), 256, 0, stream>>>(
      kv_bf, wtqB, s0T, nullptr, 8192, 64, 64, 1024, 64, 512, 8,
      (long)8192 * 1024, 64, 0, 4096, (long)8192 * 512, 64);
  // 3) scoresT[b][n][o] = scores0T[b][n][:] . W_mix[o][:]  (per b, K=512)
  gemm_nt<128, 128, 2, 2, true, false><<<dim3(4, 64, 8), 256, 0, stream>>>(
      s0T, wmixB, sw, nullptr, 8192, 512, 512, 512, 512, 512, 1,
      (long)8192 * 512, 0, 0, 0, (long)8192 * 512, 0);
  // 4) softmax over m (in-place) -> slice_wT
  softmax_m_k<<<(B_ * N_) / 32, 256, 0, stream>>>(sw);
  // 5) slice_tok accumulation + S (split-K=8, f32 atomics)
  slice_acc_k<<<512, 256, 0, stream>>>(sw, kv_bf, sacc, Ssum);
  // 5.5) normalize + layernorm -> slice_tok [B,M,D] bf16
  norm_ln_k<<<1024, 256, 0, stream>>>(sacc, Ssum, ln_g, ln_b, stokB);
  // 6a) qkv = slice_tok @ W_qkv                  [512 x 1536]
  gemm_nt<64, 64, 2, 2, true, false><<<dim3(24, 8, 1), 256, 0, stream>>>(
      stokB, wqkvT, qkvB, nullptr, 512, 1536, 512, 512, 512, 1536, 1, 0, 0, 0, 0, 0, 0);
  // 6b) mini self-attention -> out_tokT [bh][d][m]
  mini_attn_k<<<64, 256, 0, stream>>>(qkvB, otokT);
  // 7) y[b][n][h*64+d] = slice_wT[b][n][h*64+:] . out_tokT[bh][d][:]  (K=64)
  gemm_nt<128, 64, 2, 2, true, false><<<dim3(1, 64, 64), 256, 0, stream>>>(
      sw, otokT, y_bf, nullptr, 8192, 64, 64, 512, 64, 512, 8,
      (long)8192 * 512, 64, (long)8 * 4096, 4096, (long)8192 * 512, 64);
  // 8) out = y @ W_out + b_out (f32 out)         [65536 x 512]
  gemm_nt<128, 128, 2, 2, false, true><<<dim3(4, 512, 1), 256, 0, stream>>>(
      y_bf, woutT, out, b_out, 65536, 512, 512, 512, 512, 512, 1, 0, 0, 0, 0, 0, 0);
}

// Round 3
// 698.966 us; speedup vs baseline: 1.3373x; 1.3373x over previous
//
#include <hip/hip_runtime.h>

typedef unsigned short u16;
typedef unsigned int u32;
typedef __attribute__((ext_vector_type(8))) short s8v;
typedef __attribute__((ext_vector_type(8))) __bf16 b8v;
typedef __attribute__((ext_vector_type(4))) float f4v;

#define B_ 8
#define N_ 8192
#define D_ 512
#define H_ 8
#define M_ 64

__device__ __forceinline__ float bf2f(u16 u) { return __uint_as_float(((u32)u) << 16); }
__device__ __forceinline__ u16 f2bf(float f) {
  u32 x = __float_as_uint(f);
  return (u16)((x + 0x7fffu + ((x >> 16) & 1u)) >> 16);  // RNE, inputs are finite
}
__device__ __forceinline__ void unpack2(u32 u, float& a, float& b) {
  a = __uint_as_float(u << 16);
  b = __uint_as_float(u & 0xffff0000u);
}

// async global->LDS, 16B per lane (dest must be wave-uniform base + lane*16)
__device__ __forceinline__ void gload_lds16(const void* g, void* l) {
  __builtin_amdgcn_global_load_lds((const __attribute__((address_space(1))) void*)g,
                                   (__attribute__((address_space(3))) void*)l, 16, 0, 0);
}

// MFMA dispatcher: compiles whether the builtin wants short8 or __bf16x8.
template <typename V>
__device__ __forceinline__ auto mfma_sel(V a, V b, f4v c, int)
    -> decltype(__builtin_amdgcn_mfma_f32_16x16x32_bf16(a, b, c, 0, 0, 0)) {
  return __builtin_amdgcn_mfma_f32_16x16x32_bf16(a, b, c, 0, 0, 0);
}
template <typename V>
__device__ __forceinline__ f4v mfma_sel(V a, V b, f4v c, long) {
  return __builtin_amdgcn_mfma_f32_16x16x32_bf16(__builtin_bit_cast(b8v, a),
                                                 __builtin_bit_cast(b8v, b), c, 0, 0, 0);
}
__device__ __forceinline__ f4v MFMA(s8v a, s8v b, f4v c) { return mfma_sel(a, b, c, 0); }

// ---------------------------------------------------------------------------
// Generic NT GEMM: C[M x Ncol] = A[M x K] * Bt[Ncol x K]^T  (bf16 in, f32 acc)
// Batched via blockIdx.z: z -> (zb = z/zh, zr = z%zh), per-operand offsets.
// m97 structure: BK=32, double-buffered LDS, global_load_lds width 16.
// ATOMIC: f32 atomicAdd epilogue (split-K accumulation; zr can be a K-chunk).
// ---------------------------------------------------------------------------
template <int BM, int BN, int WR, int WC, bool OUTBF, bool BIAS, bool ATOMIC = false>
__launch_bounds__(256)
__global__ void gemm_nt(const u16* __restrict__ A, const u16* __restrict__ Bt,
                        void* __restrict__ Cout, const float* __restrict__ bias,
                        int M, int Ncol, int K, long lda, long ldb, long ldc, int zh,
                        long sAb, long sAh, long sBb, long sBh, long sCb, long sCh) {
  constexpr int NTH = 256;
  constexpr int WM = BM / WR, WN = BN / WC;
  constexpr int MR = WM / 16, NR = WN / 16;
  constexpr int AISS = (BM * 64) / (NTH * 16);
  constexpr int BISS = (BN * 64) / (NTH * 16);
  __shared__ __align__(16) u16 As[2][BM][32];
  __shared__ __align__(16) u16 Bs[2][BN][32];

  const int tid = threadIdx.x;
  const int z = blockIdx.z;
  const int zb = z / zh, zr = z % zh;
  const u16* Ab = A + zb * sAb + zr * sAh;
  const u16* Bb = Bt + zb * sBb + zr * sBh;
  const long tm = (long)blockIdx.y * BM;
  const long tn = (long)blockIdx.x * BN;
  const int lane = tid & 63, wid = tid >> 6;
  const int wr = wid / WC, wc = wid % WC;

  f4v acc[MR][NR] = {};

  auto stage = [&](int buf, int k0) {
#pragma unroll
    for (int i = 0; i < AISS; ++i) {
      const int t = i * NTH + tid;
      gload_lds16((const char*)Ab + ((tm + (t >> 2)) * lda + k0) * 2 + (t & 3) * 16,
                  (char*)(&As[buf][0][0]) + t * 16);
    }
#pragma unroll
    for (int i = 0; i < BISS; ++i) {
      const int t = i * NTH + tid;
      gload_lds16((const char*)Bb + ((tn + (t >> 2)) * ldb + k0) * 2 + (t & 3) * 16,
                  (char*)(&Bs[buf][0][0]) + t * 16);
    }
  };

  stage(0, 0);
  const int NK = K >> 5;
  for (int kt = 0; kt < NK; ++kt) {
    __syncthreads();  // drains vmcnt -> staged buffer ready; protects buffer reuse
    if (kt + 1 < NK) stage((kt + 1) & 1, (kt + 1) << 5);
    const int cb = kt & 1;
    s8v av[MR];
    s8v bv[NR];
#pragma unroll
    for (int i = 0; i < MR; ++i)
      av[i] = *(const s8v*)&As[cb][wr * WM + i * 16 + (lane & 15)][(lane >> 4) * 8];
#pragma unroll
    for (int j = 0; j < NR; ++j)
      bv[j] = *(const s8v*)&Bs[cb][wc * WN + j * 16 + (lane & 15)][(lane >> 4) * 8];
#pragma unroll
    for (int i = 0; i < MR; ++i) {
#pragma unroll
      for (int j = 0; j < NR; ++j) acc[i][j] = MFMA(av[i], bv[j], acc[i][j]);
    }
  }

  // C/D layout (verified m89/m91): col = lane&15, row = (lane>>4)*4 + reg
  const long zco = zb * sCb + zr * sCh;
  const long row0 = tm + wr * WM + ((lane >> 4) << 2);
  const long col0 = tn + wc * WN + (lane & 15);
#pragma unroll
  for (int i = 0; i < MR; ++i) {
#pragma unroll
    for (int j = 0; j < NR; ++j) {
#pragma unroll
      for (int r = 0; r < 4; ++r) {
        const long row = row0 + i * 16 + r;
        const long col = col0 + j * 16;
        float v = acc[i][j][r];
        if constexpr (BIAS) v += bias[col];
        if constexpr (ATOMIC)
          atomicAdd(&((float*)Cout)[zco + row * ldc + col], v);
        else if constexpr (OUTBF)
          ((u16*)Cout)[zco + row * ldc + col] = f2bf(v);
        else
          ((float*)Cout)[zco + row * ldc + col] = v;
      }
    }
  }
}

// ---------------------------------------------------------------------------
__launch_bounds__(256)
__global__ void cast_f32_bf16_k(const float* __restrict__ src, u16* __restrict__ dst, long n) {
  const long i = ((long)blockIdx.x * 256 + threadIdx.x) * 8;
  if (i >= n) return;
  const float4* s = (const float4*)(src + i);
  const float4 a = s[0], b = s[1];
  uint4 o;
  o.x = (u32)f2bf(a.x) | ((u32)f2bf(a.y) << 16);
  o.y = (u32)f2bf(a.z) | ((u32)f2bf(a.w) << 16);
  o.z = (u32)f2bf(b.x) | ((u32)f2bf(b.y) << 16);
  o.w = (u32)f2bf(b.z) | ((u32)f2bf(b.w) << 16);
  *(uint4*)(dst + i) = o;
}

__launch_bounds__(256)
__global__ void transpose_cast_k(const float* __restrict__ src, u16* __restrict__ dst, int R, int C) {
  const long idx = (long)blockIdx.x * 256 + threadIdx.x;
  if (idx >= (long)R * C) return;
  const int r = (int)(idx / C), c = (int)(idx - (long)r * C);
  dst[(long)c * R + r] = f2bf(src[idx]);
}

// softmax over m (64 contiguous values per (b,n,h)) — in place on bf16 rows
__launch_bounds__(256)
__global__ void softmax_m_k(u16* __restrict__ sw) {
  const long g = (long)blockIdx.x * 32 + (threadIdx.x >> 3);
  const int h = threadIdx.x & 7;
  u16* p = sw + g * 512 + h * 64;
  float v[64];
  const uint4* q = (const uint4*)p;
#pragma unroll
  for (int i = 0; i < 8; ++i) {
    const uint4 u = q[i];
    unpack2(u.x, v[i * 8 + 0], v[i * 8 + 1]);
    unpack2(u.y, v[i * 8 + 2], v[i * 8 + 3]);
    unpack2(u.z, v[i * 8 + 4], v[i * 8 + 5]);
    unpack2(u.w, v[i * 8 + 6], v[i * 8 + 7]);
  }
  float mx = v[0];
#pragma unroll
  for (int i = 1; i < 64; ++i) mx = fmaxf(mx, v[i]);
  float s = 0.f;
#pragma unroll
  for (int i = 0; i < 64; ++i) {
    v[i] = __expf(v[i] - mx);
    s += v[i];
  }
  const float inv = 1.f / s;
  uint4* o = (uint4*)p;
#pragma unroll
  for (int i = 0; i < 8; ++i) {
    uint4 u;
    u.x = (u32)f2bf(v[i * 8 + 0] * inv) | ((u32)f2bf(v[i * 8 + 1] * inv) << 16);
    u.y = (u32)f2bf(v[i * 8 + 2] * inv) | ((u32)f2bf(v[i * 8 + 3] * inv) << 16);
    u.z = (u32)f2bf(v[i * 8 + 4] * inv) | ((u32)f2bf(v[i * 8 + 5] * inv) << 16);
    u.w = (u32)f2bf(v[i * 8 + 6] * inv) | ((u32)f2bf(v[i * 8 + 7] * inv) << 16);
    o[i] = u;
  }
}

// ---------------------------------------------------------------------------
// LDS-tiled transpose: src[b][n][rowStride] (cols colOff + h*64 + 0..63, bf16)
//   -> dst[bh][c][n] (n contiguous). Optionally Ssum[bh*64+c] += sum_n src.
// 64x64 tile per block; grid (N/64, B*H). Pad-to-65 kills LDS bank conflicts.
// ---------------------------------------------------------------------------
template <bool DOSUM>
__launch_bounds__(256)
__global__ void transpose_hd_k(const u16* __restrict__ src, long rowStride, int colOff,
                               u16* __restrict__ dst, float* __restrict__ Ssum) {
  const int nt = blockIdx.x, bh = blockIdx.y;
  const int b = bh >> 3, h = bh & 7;
  const int t = threadIdx.x;
  __shared__ u16 lds[64][65];
  const long nbase = (long)b * N_ + (long)nt * 64;
#pragma unroll
  for (int k = 0; k < 2; ++k) {
    const int nl = (t >> 3) + 32 * k;      // source row within tile
    const int c0 = (t & 7) * 8;            // 8 contiguous source cols (16B read)
    const uint4 v = *(const uint4*)(src + (nbase + nl) * rowStride + colOff + h * 64 + c0);
    const u16* pv = (const u16*)&v;
#pragma unroll
    for (int j = 0; j < 8; ++j) lds[c0 + j][nl] = pv[j];
  }
  __syncthreads();
#pragma unroll
  for (int k = 0; k < 2; ++k) {
    const int ml = (t >> 3) + 32 * k;      // output row (= source col)
    const int n0 = (t & 7) * 8;            // 8 contiguous n (16B write)
    uint4 o;
    u16* po = (u16*)&o;
    float s = 0.f;
#pragma unroll
    for (int j = 0; j < 8; ++j) {
      po[j] = lds[ml][n0 + j];
      if (DOSUM) s += bf2f(po[j]);
    }
    *(uint4*)(dst + ((long)bh * 64 + ml) * (long)N_ + (long)nt * 64 + n0) = o;
    if (DOSUM) {
      s += __shfl_xor(s, 1);
      s += __shfl_xor(s, 2);
      s += __shfl_xor(s, 4);               // 8 lanes sharing ml
      if ((t & 7) == 0) atomicAdd(&Ssum[bh * 64 + ml], s);
    }
  }
}

// normalize by S, layernorm over d, emit slice_tok as [B, M, H*64+d] bf16
__launch_bounds__(256)
__global__ void norm_ln_k(const float* __restrict__ acc, const float* __restrict__ Ssum,
                          const float* __restrict__ g, const float* __restrict__ bb,
                          u16* __restrict__ stok) {
  const int r = blockIdx.x * 4 + (threadIdx.x >> 6);  // 0..4095 = (b,h,m)
  const int d = threadIdx.x & 63;
  const float v = acc[(long)r * 64 + d] / (Ssum[r] + 1e-5f);
  float mu = v;
#pragma unroll
  for (int k = 1; k < 64; k <<= 1) mu += __shfl_xor(mu, k);
  mu *= (1.f / 64.f);
  const float t = v - mu;
  float var = t * t;
#pragma unroll
  for (int k = 1; k < 64; k <<= 1) var += __shfl_xor(var, k);
  var *= (1.f / 64.f);
  const float o = t * rsqrtf(var + 1e-5f) * g[d] + bb[d];
  const int b = r >> 9, h = (r >> 6) & 7, m = r & 63;
  stok[((long)(b * 64 + m)) * 512 + h * 64 + d] = f2bf(o);
}

// tiny per-(b,h) self-attention over M=64 slice tokens; emits out_tok TRANSPOSED [bh][d][m]
__launch_bounds__(256)
__global__ void mini_attn_k(const u16* __restrict__ qkv, u16* __restrict__ otokT) {
  const int bh = blockIdx.x;
  const int b = bh >> 3, h = bh & 7;
  const int tid = threadIdx.x;
  __shared__ u16 qs[64][64], ks[64][64], vs[64][64];
  __shared__ float att[64][64];
  for (int idx = tid; idx < 4096; idx += 256) {
    const int mm = idx >> 6, dd = idx & 63;
    const long base = ((long)(b * 64 + mm)) * 1536 + h * 64 + dd;
    qs[mm][dd] = qkv[base];
    ks[mm][dd] = qkv[base + 512];
    vs[mm][dd] = qkv[base + 1024];
  }
  __syncthreads();
  {
    const int qi = tid >> 2, pt = tid & 3;
    for (int kk = pt * 16; kk < pt * 16 + 16; ++kk) {
      float sum = 0.f;
#pragma unroll
      for (int dd = 0; dd < 64; ++dd) sum += bf2f(qs[qi][dd]) * bf2f(ks[kk][dd]);
      att[qi][kk] = sum * 0.125f;  // HD^-0.5
    }
  }
  __syncthreads();
  if (tid < 64) {
    float mx = att[tid][0];
    for (int k = 1; k < 64; ++k) mx = fmaxf(mx, att[tid][k]);
    float s = 0.f;
    for (int k = 0; k < 64; ++k) {
      const float e = __expf(att[tid][k] - mx);
      att[tid][k] = e;
      s += e;
    }
    const float inv = 1.f / s;
    for (int k = 0; k < 64; ++k) att[tid][k] *= inv;
  }
  __syncthreads();
  {
    const int mi = tid >> 2, pt = tid & 3;
    for (int dd = pt * 16; dd < pt * 16 + 16; ++dd) {
      float sum = 0.f;
#pragma unroll
      for (int k = 0; k < 64; ++k) sum += att[mi][k] * bf2f(vs[k][dd]);
      otokT[((long)bh * 64 + dd) * 64 + mi] = f2bf(sum);
    }
  }
}

// ---------------------------------------------------------------------------
extern "C" void kernel_launch(void* const* d_in, const int* in_sizes, int n_in,
                              void* d_out, int out_size, void* d_ws, size_t ws_size,
                              hipStream_t stream) {
  const float* x = (const float*)d_in[0];
  const float* W_kv = (const float*)d_in[1];
  const float* b_kv = (const float*)d_in[2];
  const float* wtq = (const float*)d_in[3];
  const float* W_mix = (const float*)d_in[4];
  const float* ln_g = (const float*)d_in[5];
  const float* ln_b = (const float*)d_in[6];
  const float* W_qkv = (const float*)d_in[7];
  const float* W_out = (const float*)d_in[8];
  const float* b_out = (const float*)d_in[9];
  float* out = (float*)d_out;
  (void)in_sizes; (void)n_in; (void)out_size; (void)ws_size;

  char* p = (char*)d_ws;
  auto carve = [&](size_t bytes) {
    char* r = p;
    p += (bytes + 255) & ~(size_t)255;
    return r;
  };
  u16* x_bf  = (u16*)carve((size_t)B_ * N_ * D_ * 2);        // 67 MB; reused as xvT
  u16* kv_bf = (u16*)carve((size_t)B_ * N_ * 2 * D_ * 2);    // 134 MB
  u16* sw    = (u16*)carve((size_t)B_ * N_ * 512 * 2);       // scoresT -> slice_wT (in-place)
  u16* s0T   = (u16*)carve((size_t)B_ * N_ * 512 * 2);       // scores0T; reused as wT, then y_bf
  u16* wkvT  = (u16*)carve((size_t)1024 * 512 * 2);
  u16* wqkvT = (u16*)carve((size_t)1536 * 512 * 2);
  u16* woutT = (u16*)carve((size_t)512 * 512 * 2);
  u16* wmixB = (u16*)carve((size_t)512 * 512 * 2);
  u16* wtqB  = (u16*)carve((size_t)512 * 64 * 2);
  float* sacc = (float*)carve((size_t)4096 * 64 * 4);        // 1 MB (f32 split-K acc)
  float* Ssum = (float*)carve((size_t)4096 * 4);
  u16* stokB = (u16*)carve((size_t)512 * 512 * 2);
  u16* qkvB  = (u16*)carve((size_t)512 * 1536 * 2);
  u16* otokT = (u16*)carve((size_t)4096 * 64 * 2);
  u16* y_bf = s0T;
  u16* wT   = s0T;   // [bh][m][n]  (alive: after stage 4 until stage 5)
  u16* xvT  = x_bf;  // [bh][d][n]  (alive: after stage 1 until stage 5)

  // input casts / weight transposes (all GEMMs are NT: A[M][K], Bt[N][K])
  cast_f32_bf16_k<<<(B_ * N_ * D_) / 2048, 256, 0, stream>>>(x, x_bf, (long)B_ * N_ * D_);
  transpose_cast_k<<<(512 * 1024) / 256, 256, 0, stream>>>(W_kv, wkvT, 512, 1024);
  transpose_cast_k<<<(512 * 1536) / 256, 256, 0, stream>>>(W_qkv, wqkvT, 512, 1536);
  transpose_cast_k<<<(512 * 512) / 256, 256, 0, stream>>>(W_out, woutT, 512, 512);
  cast_f32_bf16_k<<<(512 * 512) / 2048, 256, 0, stream>>>(W_mix, wmixB, 512 * 512);
  cast_f32_bf16_k<<<(512 * 64) / 2048, 256, 0, stream>>>(wtq, wtqB, 512 * 64);
  hipMemsetAsync(sacc, 0, (size_t)4096 * 64 * 4 + (size_t)4096 * 4, stream);

  // 1) kv = x @ W_kv + b_kv                      [65536 x 1024]
  gemm_nt<128, 128, 2, 2, true, true><<<dim3(8, 512, 1), 256, 0, stream>>>(
      x_bf, wkvT, kv_bf, b_kv, 65536, 1024, 512, 512, 512, 1024, 1, 0, 0, 0, 0, 0, 0);
  // 1.5) xvT[bh][d][n] <- kv v-half (x_bf is dead now; stream order protects it)
  transpose_hd_k<false><<<dim3(128, 64), 256, 0, stream>>>(kv_bf, 1024, 512, xvT, nullptr);
  // 2) scores0T[b][n][h*64+m] = xk[b,h,n,:] . wtq[h,m,:]   (per (b,h), K=64)
  gemm_nt<128, 64, 2, 2, true, false><<<dim3(1, 64, 64), 256, 0, stream>>>(
      kv_bf, wtqB, s0T, nullptr, 8192, 64, 64, 1024, 64, 512, 8,
      (long)8192 * 1024, 64, 0, 4096, (long)8192 * 512, 64);
  // 3) scoresT[b][n][o] = scores0T[b][n][:] . W_mix[o][:]  (per b, K=512)
  gemm_nt<128, 128, 2, 2, true, false><<<dim3(4, 64, 8), 256, 0, stream>>>(
      s0T, wmixB, sw, nullptr, 8192, 512, 512, 512, 512, 512, 1,
      (long)8192 * 512, 0, 0, 0, (long)8192 * 512, 0);
  // 4) softmax over m (in-place) -> slice_wT
  softmax_m_k<<<(B_ * N_) / 32, 256, 0, stream>>>(sw);
  // 4.5) wT[bh][m][n] <- slice_wT, fused Ssum (s0T dead after stage 3)
  transpose_hd_k<true><<<dim3(128, 64), 256, 0, stream>>>(sw, 512, 0, wT, Ssum);
  // 5) slice_tok = wT @ xvT^T per bh, split-K=16, f32 atomic accumulate
  gemm_nt<64, 64, 2, 2, false, false, true><<<dim3(1, 1, 1024), 256, 0, stream>>>(
      wT, xvT, sacc, nullptr, 64, 64, 512, N_, N_, 64, 16,
      (long)64 * N_, 512, (long)64 * N_, 512, 4096, 0);
  // 5.5) normalize + layernorm -> slice_tok [B,M,D] bf16
  norm_ln_k<<<1024, 256, 0, stream>>>(sacc, Ssum, ln_g, ln_b, stokB);
  // 6a) qkv = slice_tok @ W_qkv                  [512 x 1536]
  gemm_nt<64, 64, 2, 2, true, false><<<dim3(24, 8, 1), 256, 0, stream>>>(
      stokB, wqkvT, qkvB, nullptr, 512, 1536, 512, 512, 512, 1536, 1, 0, 0, 0, 0, 0, 0);
  // 6b) mini self-attention -> out_tokT [bh][d][m]
  mini_attn_k<<<64, 256, 0, stream>>>(qkvB, otokT);
  // 7) y[b][n][h*64+d] = slice_wT[b][n][h*64+:] . out_tokT[bh][d][:]  (K=64)
  gemm_nt<128, 64, 2, 2, true, false><<<dim3(1, 64, 64), 256, 0, stream>>>(
      sw, otokT, y_bf, nullptr, 8192, 64, 64, 512, 64, 512, 8,
      (long)8192 * 512, 64, (long)8 * 4096, 4096, (long)8192 * 512, 64);
  // 8) out = y @ W_out + b_out (f32 out)         [65536 x 512]
  gemm_nt<128, 128, 2, 2, false, true><<<dim3(4, 512, 1), 256, 0, stream>>>(
      y_bf, woutT, out, b_out, 65536, 512, 512, 512, 512, 512, 1, 0, 0, 0, 0, 0, 0);
}

// Round 5
// 671.705 us; speedup vs baseline: 1.3916x; 1.0406x over previous
//
#include <hip/hip_runtime.h>

typedef unsigned short u16;
typedef unsigned int u32;
typedef __attribute__((ext_vector_type(8))) short s8v;
typedef __attribute__((ext_vector_type(8))) __bf16 b8v;
typedef __attribute__((ext_vector_type(4))) float f4v;

#define B_ 8
#define N_ 8192
#define D_ 512
#define H_ 8
#define M_ 64

__device__ __forceinline__ float bf2f(u16 u) { return __uint_as_float(((u32)u) << 16); }
__device__ __forceinline__ u16 f2bf(float f) {
  u32 x = __float_as_uint(f);
  return (u16)((x + 0x7fffu + ((x >> 16) & 1u)) >> 16);  // RNE, inputs are finite
}
__device__ __forceinline__ void unpack2(u32 u, float& a, float& b) {
  a = __uint_as_float(u << 16);
  b = __uint_as_float(u & 0xffff0000u);
}

// async global->LDS, 16B per lane (dest must be wave-uniform base + lane*16)
__device__ __forceinline__ void gload_lds16(const void* g, void* l) {
  __builtin_amdgcn_global_load_lds((const __attribute__((address_space(1))) void*)g,
                                   (__attribute__((address_space(3))) void*)l, 16, 0, 0);
}

// MFMA dispatcher: compiles whether the builtin wants short8 or __bf16x8.
template <typename V>
__device__ __forceinline__ auto mfma_sel(V a, V b, f4v c, int)
    -> decltype(__builtin_amdgcn_mfma_f32_16x16x32_bf16(a, b, c, 0, 0, 0)) {
  return __builtin_amdgcn_mfma_f32_16x16x32_bf16(a, b, c, 0, 0, 0);
}
template <typename V>
__device__ __forceinline__ f4v mfma_sel(V a, V b, f4v c, long) {
  return __builtin_amdgcn_mfma_f32_16x16x32_bf16(__builtin_bit_cast(b8v, a),
                                                 __builtin_bit_cast(b8v, b), c, 0, 0, 0);
}
__device__ __forceinline__ f4v MFMA(s8v a, s8v b, f4v c) { return mfma_sel(a, b, c, 0); }

// ---------------------------------------------------------------------------
// Generic NT GEMM: C[M x Ncol] = A[M x K] * Bt[Ncol x K]^T  (bf16 in, f32 acc)
// Batched via blockIdx.z: z -> (zb = z/zh, zr = z%zh), per-operand offsets.
// m97 structure: BK=32, double-buffered LDS, global_load_lds width 16.
// ATOMIC: f32 atomicAdd epilogue (split-K accumulation; zr can be a K-chunk).
// T1 XCD swizzle (m204 bijective): each XCD gets a contiguous chunk of the
// x-fastest tile order, so the col-tiles sharing an A row-panel co-reside in
// one XCD's L2 (round-3 counters: 4x A over-fetch without this).
// ---------------------------------------------------------------------------
template <int BM, int BN, int WR, int WC, bool OUTBF, bool BIAS, bool ATOMIC = false>
__launch_bounds__(256)
__global__ void gemm_nt(const u16* __restrict__ A, const u16* __restrict__ Bt,
                        void* __restrict__ Cout, const float* __restrict__ bias,
                        int M, int Ncol, int K, long lda, long ldb, long ldc, int zh,
                        long sAb, long sAh, long sBb, long sBh, long sCb, long sCh) {
  constexpr int NTH = 256;
  constexpr int WM = BM / WR, WN = BN / WC;
  constexpr int MR = WM / 16, NR = WN / 16;
  constexpr int AISS = (BM * 64) / (NTH * 16);
  constexpr int BISS = (BN * 64) / (NTH * 16);
  __shared__ __align__(16) u16 As[2][BM][32];
  __shared__ __align__(16) u16 Bs[2][BN][32];

  const int tid = threadIdx.x;

  // --- T1: XCD-aware bijective block remap (m204) ---
  const u32 nwg = gridDim.x * gridDim.y * gridDim.z;
  const u32 f = blockIdx.x + gridDim.x * (blockIdx.y + gridDim.y * blockIdx.z);
  const u32 q = nwg >> 3, r = nwg & 7, xcd = f & 7;
  const u32 orig = (xcd < r ? xcd * (q + 1) : r * (q + 1) + (xcd - r) * q) + (f >> 3);
  const u32 bx = orig % gridDim.x;
  const u32 t1g = orig / gridDim.x;
  const u32 by = t1g % gridDim.y;
  const u32 bz = t1g / gridDim.y;

  const int z = bz;
  const int zb = z / zh, zr = z % zh;
  const u16* Ab = A + zb * sAb + zr * sAh;
  const u16* Bb = Bt + zb * sBb + zr * sBh;
  const long tm = (long)by * BM;
  const long tn = (long)bx * BN;
  const int lane = tid & 63, wid = tid >> 6;
  const int wr = wid / WC, wc = wid % WC;

  f4v acc[MR][NR] = {};

  auto stage = [&](int buf, int k0) {
#pragma unroll
    for (int i = 0; i < AISS; ++i) {
      const int t = i * NTH + tid;
      gload_lds16((const char*)Ab + ((tm + (t >> 2)) * lda + k0) * 2 + (t & 3) * 16,
                  (char*)(&As[buf][0][0]) + t * 16);
    }
#pragma unroll
    for (int i = 0; i < BISS; ++i) {
      const int t = i * NTH + tid;
      gload_lds16((const char*)Bb + ((tn + (t >> 2)) * ldb + k0) * 2 + (t & 3) * 16,
                  (char*)(&Bs[buf][0][0]) + t * 16);
    }
  };

  stage(0, 0);
  const int NK = K >> 5;
  for (int kt = 0; kt < NK; ++kt) {
    __syncthreads();  // drains vmcnt -> staged buffer ready; protects buffer reuse
    if (kt + 1 < NK) stage((kt + 1) & 1, (kt + 1) << 5);
    const int cb = kt & 1;
    s8v av[MR];
    s8v bv[NR];
#pragma unroll
    for (int i = 0; i < MR; ++i)
      av[i] = *(const s8v*)&As[cb][wr * WM + i * 16 + (lane & 15)][(lane >> 4) * 8];
#pragma unroll
    for (int j = 0; j < NR; ++j)
      bv[j] = *(const s8v*)&Bs[cb][wc * WN + j * 16 + (lane & 15)][(lane >> 4) * 8];
#pragma unroll
    for (int i = 0; i < MR; ++i) {
#pragma unroll
      for (int j = 0; j < NR; ++j) acc[i][j] = MFMA(av[i], bv[j], acc[i][j]);
    }
  }

  // C/D layout (verified m89/m91): col = lane&15, row = (lane>>4)*4 + reg
  const long zco = zb * sCb + zr * sCh;
  const long row0 = tm + wr * WM + ((lane >> 4) << 2);
  const long col0 = tn + wc * WN + (lane & 15);
#pragma unroll
  for (int i = 0; i < MR; ++i) {
#pragma unroll
    for (int j = 0; j < NR; ++j) {
#pragma unroll
      for (int r4 = 0; r4 < 4; ++r4) {
        const long row = row0 + i * 16 + r4;
        const long col = col0 + j * 16;
        float v = acc[i][j][r4];
        if constexpr (BIAS) v += bias[col];
        if constexpr (ATOMIC)
          atomicAdd(&((float*)Cout)[zco + row * ldc + col], v);
        else if constexpr (OUTBF)
          ((u16*)Cout)[zco + row * ldc + col] = f2bf(v);
        else
          ((float*)Cout)[zco + row * ldc + col] = v;
      }
    }
  }
}

// ---------------------------------------------------------------------------
__launch_bounds__(256)
__global__ void cast_f32_bf16_k(const float* __restrict__ src, u16* __restrict__ dst, long n) {
  const long i = ((long)blockIdx.x * 256 + threadIdx.x) * 8;
  if (i >= n) return;
  const float4* s = (const float4*)(src + i);
  const float4 a = s[0], b = s[1];
  uint4 o;
  o.x = (u32)f2bf(a.x) | ((u32)f2bf(a.y) << 16);
  o.y = (u32)f2bf(a.z) | ((u32)f2bf(a.w) << 16);
  o.z = (u32)f2bf(b.x) | ((u32)f2bf(b.y) << 16);
  o.w = (u32)f2bf(b.z) | ((u32)f2bf(b.w) << 16);
  *(uint4*)(dst + i) = o;
}

__launch_bounds__(256)
__global__ void transpose_cast_k(const float* __restrict__ src, u16* __restrict__ dst, int R, int C) {
  const long idx = (long)blockIdx.x * 256 + threadIdx.x;
  if (idx >= (long)R * C) return;
  const int r = (int)(idx / C), c = (int)(idx - (long)r * C);
  dst[(long)c * R + r] = f2bf(src[idx]);
}

// softmax over m (64 contiguous values per (b,n,h)) — in place on bf16 rows
__launch_bounds__(256)
__global__ void softmax_m_k(u16* __restrict__ sw) {
  const long g = (long)blockIdx.x * 32 + (threadIdx.x >> 3);
  const int h = threadIdx.x & 7;
  u16* p = sw + g * 512 + h * 64;
  float v[64];
  const uint4* q = (const uint4*)p;
#pragma unroll
  for (int i = 0; i < 8; ++i) {
    const uint4 u = q[i];
    unpack2(u.x, v[i * 8 + 0], v[i * 8 + 1]);
    unpack2(u.y, v[i * 8 + 2], v[i * 8 + 3]);
    unpack2(u.z, v[i * 8 + 4], v[i * 8 + 5]);
    unpack2(u.w, v[i * 8 + 6], v[i * 8 + 7]);
  }
  float mx = v[0];
#pragma unroll
  for (int i = 1; i < 64; ++i) mx = fmaxf(mx, v[i]);
  float s = 0.f;
#pragma unroll
  for (int i = 0; i < 64; ++i) {
    v[i] = __expf(v[i] - mx);
    s += v[i];
  }
  const float inv = 1.f / s;
  uint4* o = (uint4*)p;
#pragma unroll
  for (int i = 0; i < 8; ++i) {
    uint4 u;
    u.x = (u32)f2bf(v[i * 8 + 0] * inv) | ((u32)f2bf(v[i * 8 + 1] * inv) << 16);
    u.y = (u32)f2bf(v[i * 8 + 2] * inv) | ((u32)f2bf(v[i * 8 + 3] * inv) << 16);
    u.z = (u32)f2bf(v[i * 8 + 4] * inv) | ((u32)f2bf(v[i * 8 + 5] * inv) << 16);
    u.w = (u32)f2bf(v[i * 8 + 6] * inv) | ((u32)f2bf(v[i * 8 + 7] * inv) << 16);
    o[i] = u;
  }
}

// ---------------------------------------------------------------------------
// LDS-tiled transpose: src[b][n][rowStride] (cols colOff + h*64 + 0..63, bf16)
//   -> dst[bh][c][n] (n contiguous). Optionally Ssum[bh*64+c] += sum_n src.
// 64x64 tile per block; grid (N/64, B*H). Pad-to-65 kills LDS bank conflicts.
// ---------------------------------------------------------------------------
template <bool DOSUM>
__launch_bounds__(256)
__global__ void transpose_hd_k(const u16* __restrict__ src, long rowStride, int colOff,
                               u16* __restrict__ dst, float* __restrict__ Ssum) {
  const int nt = blockIdx.x, bh = blockIdx.y;
  const int b = bh >> 3, h = bh & 7;
  const int t = threadIdx.x;
  __shared__ u16 lds[64][65];
  const long nbase = (long)b * N_ + (long)nt * 64;
#pragma unroll
  for (int k = 0; k < 2; ++k) {
    const int nl = (t >> 3) + 32 * k;      // source row within tile
    const int c0 = (t & 7) * 8;            // 8 contiguous source cols (16B read)
    const uint4 v = *(const uint4*)(src + (nbase + nl) * rowStride + colOff + h * 64 + c0);
    const u16* pv = (const u16*)&v;
#pragma unroll
    for (int j = 0; j < 8; ++j) lds[c0 + j][nl] = pv[j];
  }
  __syncthreads();
#pragma unroll
  for (int k = 0; k < 2; ++k) {
    const int ml = (t >> 3) + 32 * k;      // output row (= source col)
    const int n0 = (t & 7) * 8;            // 8 contiguous n (16B write)
    uint4 o;
    u16* po = (u16*)&o;
    float s = 0.f;
#pragma unroll
    for (int j = 0; j < 8; ++j) {
      po[j] = lds[ml][n0 + j];
      if (DOSUM) s += bf2f(po[j]);
    }
    *(uint4*)(dst + ((long)bh * 64 + ml) * (long)N_ + (long)nt * 64 + n0) = o;
    if (DOSUM) {
      s += __shfl_xor(s, 1);
      s += __shfl_xor(s, 2);
      s += __shfl_xor(s, 4);               // 8 lanes sharing ml
      if ((t & 7) == 0) atomicAdd(&Ssum[bh * 64 + ml], s);
    }
  }
}

// normalize by S, layernorm over d, emit slice_tok as [B, M, H*64+d] bf16
__launch_bounds__(256)
__global__ void norm_ln_k(const float* __restrict__ acc, const float* __restrict__ Ssum,
                          const float* __restrict__ g, const float* __restrict__ bb,
                          u16* __restrict__ stok) {
  const int r = blockIdx.x * 4 + (threadIdx.x >> 6);  // 0..4095 = (b,h,m)
  const int d = threadIdx.x & 63;
  const float v = acc[(long)r * 64 + d] / (Ssum[r] + 1e-5f);
  float mu = v;
#pragma unroll
  for (int k = 1; k < 64; k <<= 1) mu += __shfl_xor(mu, k);
  mu *= (1.f / 64.f);
  const float t = v - mu;
  float var = t * t;
#pragma unroll
  for (int k = 1; k < 64; k <<= 1) var += __shfl_xor(var, k);
  var *= (1.f / 64.f);
  const float o = t * rsqrtf(var + 1e-5f) * g[d] + bb[d];
  const int b = r >> 9, h = (r >> 6) & 7, m = r & 63;
  stok[((long)(b * 64 + m)) * 512 + h * 64 + d] = f2bf(o);
}

// tiny per-(b,h) self-attention over M=64 slice tokens; emits out_tok TRANSPOSED [bh][d][m]
__launch_bounds__(256)
__global__ void mini_attn_k(const u16* __restrict__ qkv, u16* __restrict__ otokT) {
  const int bh = blockIdx.x;
  const int b = bh >> 3, h = bh & 7;
  const int tid = threadIdx.x;
  __shared__ u16 qs[64][64], ks[64][64], vs[64][64];
  __shared__ float att[64][64];
  for (int idx = tid; idx < 4096; idx += 256) {
    const int mm = idx >> 6, dd = idx & 63;
    const long base = ((long)(b * 64 + mm)) * 1536 + h * 64 + dd;
    qs[mm][dd] = qkv[base];
    ks[mm][dd] = qkv[base + 512];
    vs[mm][dd] = qkv[base + 1024];
  }
  __syncthreads();
  {
    const int qi = tid >> 2, pt = tid & 3;
    for (int kk = pt * 16; kk < pt * 16 + 16; ++kk) {
      float sum = 0.f;
#pragma unroll
      for (int dd = 0; dd < 64; ++dd) sum += bf2f(qs[qi][dd]) * bf2f(ks[kk][dd]);
      att[qi][kk] = sum * 0.125f;  // HD^-0.5
    }
  }
  __syncthreads();
  if (tid < 64) {
    float mx = att[tid][0];
    for (int k = 1; k < 64; ++k) mx = fmaxf(mx, att[tid][k]);
    float s = 0.f;
    for (int k = 0; k < 64; ++k) {
      const float e = __expf(att[tid][k] - mx);
      att[tid][k] = e;
      s += e;
    }
    const float inv = 1.f / s;
    for (int k = 0; k < 64; ++k) att[tid][k] *= inv;
  }
  __syncthreads();
  {
    const int mi = tid >> 2, pt = tid & 3;
    for (int dd = pt * 16; dd < pt * 16 + 16; ++dd) {
      float sum = 0.f;
#pragma unroll
      for (int k = 0; k < 64; ++k) sum += att[mi][k] * bf2f(vs[k][dd]);
      otokT[((long)bh * 64 + dd) * 64 + mi] = f2bf(sum);
    }
  }
}

// ---------------------------------------------------------------------------
extern "C" void kernel_launch(void* const* d_in, const int* in_sizes, int n_in,
                              void* d_out, int out_size, void* d_ws, size_t ws_size,
                              hipStream_t stream) {
  const float* x = (const float*)d_in[0];
  const float* W_kv = (const float*)d_in[1];
  const float* b_kv = (const float*)d_in[2];
  const float* wtq = (const float*)d_in[3];
  const float* W_mix = (const float*)d_in[4];
  const float* ln_g = (const float*)d_in[5];
  const float* ln_b = (const float*)d_in[6];
  const float* W_qkv = (const float*)d_in[7];
  const float* W_out = (const float*)d_in[8];
  const float* b_out = (const float*)d_in[9];
  float* out = (float*)d_out;
  (void)in_sizes; (void)n_in; (void)out_size; (void)ws_size;

  char* p = (char*)d_ws;
  auto carve = [&](size_t bytes) {
    char* r = p;
    p += (bytes + 255) & ~(size_t)255;
    return r;
  };
  u16* x_bf  = (u16*)carve((size_t)B_ * N_ * D_ * 2);        // 67 MB; reused as xvT
  u16* kv_bf = (u16*)carve((size_t)B_ * N_ * 2 * D_ * 2);    // 134 MB
  u16* sw    = (u16*)carve((size_t)B_ * N_ * 512 * 2);       // scoresT -> slice_wT (in-place)
  u16* s0T   = (u16*)carve((size_t)B_ * N_ * 512 * 2);       // scores0T; reused as wT, then y_bf
  u16* wkvT  = (u16*)carve((size_t)1024 * 512 * 2);
  u16* wqkvT = (u16*)carve((size_t)1536 * 512 * 2);
  u16* woutT = (u16*)carve((size_t)512 * 512 * 2);
  u16* wmixB = (u16*)carve((size_t)512 * 512 * 2);
  u16* wtqB  = (u16*)carve((size_t)512 * 64 * 2);
  float* sacc = (float*)carve((size_t)4096 * 64 * 4);        // 1 MB (f32 split-K acc)
  float* Ssum = (float*)carve((size_t)4096 * 4);
  u16* stokB = (u16*)carve((size_t)512 * 512 * 2);
  u16* qkvB  = (u16*)carve((size_t)512 * 1536 * 2);
  u16* otokT = (u16*)carve((size_t)4096 * 64 * 2);
  u16* y_bf = s0T;
  u16* wT   = s0T;   // [bh][m][n]  (alive: after stage 4 until stage 5)
  u16* xvT  = x_bf;  // [bh][d][n]  (alive: after stage 1 until stage 5)

  // input casts / weight transposes (all GEMMs are NT: A[M][K], Bt[N][K])
  cast_f32_bf16_k<<<(B_ * N_ * D_) / 2048, 256, 0, stream>>>(x, x_bf, (long)B_ * N_ * D_);
  transpose_cast_k<<<(512 * 1024) / 256, 256, 0, stream>>>(W_kv, wkvT, 512, 1024);
  transpose_cast_k<<<(512 * 1536) / 256, 256, 0, stream>>>(W_qkv, wqkvT, 512, 1536);
  transpose_cast_k<<<(512 * 512) / 256, 256, 0, stream>>>(W_out, woutT, 512, 512);
  cast_f32_bf16_k<<<(512 * 512) / 2048, 256, 0, stream>>>(W_mix, wmixB, 512 * 512);
  cast_f32_bf16_k<<<(512 * 64) / 2048, 256, 0, stream>>>(wtq, wtqB, 512 * 64);
  hipMemsetAsync(sacc, 0, (size_t)4096 * 64 * 4 + (size_t)4096 * 4, stream);

  // 1) kv = x @ W_kv + b_kv                      [65536 x 1024]
  gemm_nt<128, 128, 2, 2, true, true><<<dim3(8, 512, 1), 256, 0, stream>>>(
      x_bf, wkvT, kv_bf, b_kv, 65536, 1024, 512, 512, 512, 1024, 1, 0, 0, 0, 0, 0, 0);
  // 1.5) xvT[bh][d][n] <- kv v-half (x_bf is dead now; stream order protects it)
  transpose_hd_k<false><<<dim3(128, 64), 256, 0, stream>>>(kv_bf, 1024, 512, xvT, nullptr);
  // 2) scores0T[b][n][h*64+m] = xk[b,h,n,:] . wtq[h,m,:]   (per (b,h), K=64)
  gemm_nt<128, 64, 2, 2, true, false><<<dim3(1, 64, 64), 256, 0, stream>>>(
      kv_bf, wtqB, s0T, nullptr, 8192, 64, 64, 1024, 64, 512, 8,
      (long)8192 * 1024, 64, 0, 4096, (long)8192 * 512, 64);
  // 3) scoresT[b][n][o] = scores0T[b][n][:] . W_mix[o][:]  (per b, K=512)
  gemm_nt<128, 128, 2, 2, true, false><<<dim3(4, 64, 8), 256, 0, stream>>>(
      s0T, wmixB, sw, nullptr, 8192, 512, 512, 512, 512, 512, 1,
      (long)8192 * 512, 0, 0, 0, (long)8192 * 512, 0);
  // 4) softmax over m (in-place) -> slice_wT
  softmax_m_k<<<(B_ * N_) / 32, 256, 0, stream>>>(sw);
  // 4.5) wT[bh][m][n] <- slice_wT, fused Ssum (s0T dead after stage 3)
  transpose_hd_k<true><<<dim3(128, 64), 256, 0, stream>>>(sw, 512, 0, wT, Ssum);
  // 5) slice_tok = wT @ xvT^T per bh, split-K=16, f32 atomic accumulate
  gemm_nt<64, 64, 2, 2, false, false, true><<<dim3(1, 1, 1024), 256, 0, stream>>>(
      wT, xvT, sacc, nullptr, 64, 64, 512, N_, N_, 64, 16,
      (long)64 * N_, 512, (long)64 * N_, 512, 4096, 0);
  // 5.5) normalize + layernorm -> slice_tok [B,M,D] bf16
  norm_ln_k<<<1024, 256, 0, stream>>>(sacc, Ssum, ln_g, ln_b, stokB);
  // 6a) qkv = slice_tok @ W_qkv                  [512 x 1536]
  gemm_nt<64, 64, 2, 2, true, false><<<dim3(24, 8, 1), 256, 0, stream>>>(
      stokB, wqkvT, qkvB, nullptr, 512, 1536, 512, 512, 512, 1536, 1, 0, 0, 0, 0, 0, 0);
  // 6b) mini self-attention -> out_tokT [bh][d][m]
  mini_attn_k<<<64, 256, 0, stream>>>(qkvB, otokT);
  // 7) y[b][n][h*64+d] = slice_wT[b][n][h*64+:] . out_tokT[bh][d][:]  (K=64)
  gemm_nt<128, 64, 2, 2, true, false><<<dim3(1, 64, 64), 256, 0, stream>>>(
      sw, otokT, y_bf, nullptr, 8192, 64, 64, 512, 64, 512, 8,
      (long)8192 * 512, 64, (long)8 * 4096, 4096, (long)8192 * 512, 64);
  // 8) out = y @ W_out + b_out (f32 out)         [65536 x 512]
  gemm_nt<128, 128, 2, 2, false, true><<<dim3(4, 512, 1), 256, 0, stream>>>(
      y_bf, woutT, out, b_out, 65536, 512, 512, 512, 512, 512, 1, 0, 0, 0, 0, 0, 0);
}